// Round 7
// baseline (38.611 us; speedup 1.0000x reference)
//
#include <hip/hip_runtime.h>

#define NN 4
#define CC 128
#define HH 64
#define WW 64
#define KK 5
#define K2 25
#define HUP 128
#define WUP 128

typedef int   v4i __attribute__((ext_vector_type(4)));
typedef float v4f __attribute__((ext_vector_type(4)));
typedef float v2f __attribute__((ext_vector_type(2)));

// Raw buffer ops: HW bounds-check (OOB load -> 0.0f, OOB store dropped).
__device__ float llvm_amdgcn_raw_buffer_load_fp32(v4i srsrc, int voffset,
                                                  int soffset, int aux)
    __asm("llvm.amdgcn.raw.buffer.load.f32");
__device__ v4f llvm_amdgcn_raw_buffer_load_v4f32(v4i srsrc, int voffset,
                                                 int soffset, int aux)
    __asm("llvm.amdgcn.raw.buffer.load.v4f32");
__device__ void llvm_amdgcn_raw_buffer_store_v2f32(v2f data, v4i srsrc,
                                                   int voffset, int soffset,
                                                   int aux)
    __asm("llvm.amdgcn.raw.buffer.store.v2f32");

__device__ inline v4i make_srd(const void* p, unsigned bytes) {
  union { const void* p; unsigned u[2]; } a;
  a.p = p;
  v4i r;
  r.x = (int)a.u[0];
  r.y = (int)(a.u[1] & 0xffffu);  // base[47:32], stride=0
  r.z = (int)bytes;               // num_records in bytes
  r.w = 0x00020000;               // raw dword access
  return r;
}

// Pack two f32 masks into one VGPR as 2x bf16 (round-half-up). Masks are
// U(0,1) positive; rel err <= 2^-9 -> output abs err ~0.04 << 0.36 threshold.
__device__ inline unsigned pack_bf16x2(float x, float y) {
  const unsigned ux = (__float_as_uint(x) + 0x8000u) >> 16;
  const unsigned uy = (__float_as_uint(y) + 0x8000u) & 0xffff0000u;
  return uy | ux;
}

// grid: NN*HH*4 = 1024 blocks, 256 threads. Masks bf16-packed (50 VGPRs vs
// 100) -> ~90 live VGPRs -> 5 waves/SIMD for latency hiding via TLP.
// block: cq = bid&3, h = (bid>>2)&63, n = bid>>8
// thread: w = t&63 (output pair 2w,2w+1), cg = t>>6; c = cq*32 + ci*4 + cg
__global__ __launch_bounds__(256, 5) void carafe_kernel(
    const float* __restrict__ feat, const float* __restrict__ masks,
    float* __restrict__ out) {
  const int bid = blockIdx.x;
  const int cq = bid & 3;
  const int h  = (bid >> 2) & (HH - 1);
  const int n  = bid >> 8;
  const int t  = threadIdx.x;
  const int w  = t & (WW - 1);
  const int cg = t >> 6;

  // Validity of window taps (zero-padding folded into the mask registers).
  float vi[KK], vj[KK];
#pragma unroll
  for (int i = 0; i < KK; ++i) {
    const int r = h - 2 + i;
    vi[i] = (r >= 0 && r < HH) ? 1.f : 0.f;
    const int x = w - 2 + i;
    vj[i] = (x >= 0 && x < WW) ? 1.f : 0.f;
  }

  // mp[k][a] = bf16x2{ masks[n,k,2h+a,2w], masks[n,k,2h+a,2w+1] } * valid(i,j)
  unsigned mp[K2][2];
#pragma unroll
  for (int k = 0; k < K2; ++k) {
    const int i = k / KK, j = k % KK;
    const float vv = vi[i] * vj[j];
#pragma unroll
    for (int a = 0; a < 2; ++a) {
      const float2 mv = *reinterpret_cast<const float2*>(
          &masks[(((size_t)n * K2 + k) * HUP + (2 * h + a)) * WUP + 2 * w]);
      mp[k][a] = pack_bf16x2(mv.x * vv, mv.y * vv);
    }
  }

  const v4i srdF = make_srd(feat, (unsigned)(NN * CC * HH * WW) * 4u);
  const v4i srdO = make_srd(out,  (unsigned)(NN * CC * HUP * WUP) * 4u);

  const int c = cq * 32 + cg;
  // Byte offset of window origin (h-2, w-2); negative only when c==0 (ci==0).
  int vfb = (((n * CC + c) * HH * WW) + (h - 2) * WW + (w - 2)) * 4;
  int vob = (((n * CC + c) * HUP + 2 * h) * WUP + 2 * w) * 4;

  // Unpack-at-use FMA. The asm barrier redefines the packed words each
  // iteration so LICM/CSE cannot hoist 100 unpacked floats out of the loop.
#define FMA1(k, e)                                                       \
  do {                                                                   \
    unsigned p0 = mp[k][0], p1 = mp[k][1];                               \
    asm volatile("" : "+v"(p0), "+v"(p1));                               \
    v2f m0, m1;                                                          \
    m0.x = __uint_as_float(p0 << 16);                                    \
    m0.y = __uint_as_float(p0 & 0xffff0000u);                            \
    m1.x = __uint_as_float(p1 << 16);                                    \
    m1.y = __uint_as_float(p1 & 0xffff0000u);                            \
    v2f ff; ff.x = (e); ff.y = (e);                                      \
    acc0 += ff * m0; acc1 += ff * m1;                                    \
  } while (0)

#define FMA5(kb, e0, e1, e2, e3, e4)                                     \
  do {                                                                   \
    FMA1((kb) + 0, (e0)); FMA1((kb) + 1, (e1)); FMA1((kb) + 2, (e2));    \
    FMA1((kb) + 3, (e3)); FMA1((kb) + 4, (e4));                          \
  } while (0)

  // --- ci = 0: scalar taps (negative voffset -> OOB -> 0 = zero padding),
  // row-split to cap live window regs. R4-proven addressing. ---
  {
    v2f acc0 = {0.f, 0.f}, acc1 = {0.f, 0.f};
    float fA[15];
#pragma unroll
    for (int i = 0; i < 3; ++i)
#pragma unroll
      for (int j = 0; j < KK; ++j)
        fA[i * KK + j] = llvm_amdgcn_raw_buffer_load_fp32(
            srdF, vfb + (i * WW + j) * 4, 0, 0);
    FMA5(0,  fA[0],  fA[1],  fA[2],  fA[3],  fA[4]);
    FMA5(5,  fA[5],  fA[6],  fA[7],  fA[8],  fA[9]);
    FMA5(10, fA[10], fA[11], fA[12], fA[13], fA[14]);

    float fB[10];
#pragma unroll
    for (int i = 0; i < 2; ++i)
#pragma unroll
      for (int j = 0; j < KK; ++j)
        fB[i * KK + j] = llvm_amdgcn_raw_buffer_load_fp32(
            srdF, vfb + ((i + 3) * WW + j) * 4, 0, 0);
    FMA5(15, fB[0], fB[1], fB[2], fB[3], fB[4]);
    FMA5(20, fB[5], fB[6], fB[7], fB[8], fB[9]);

    llvm_amdgcn_raw_buffer_store_v2f32(acc0, srdO, vob, 0, 0);
    llvm_amdgcn_raw_buffer_store_v2f32(acc1, srdO, vob + WUP * 4, 0, 0);
  }

  // --- ci = 1..7: R4-proven rolled loop. c >= 4 so voffsets positive; edge
  // crossings read in-bounds garbage annihilated by validity-zeroed masks. ---
#pragma unroll 1
  for (int ci = 1; ci < 8; ++ci) {
    vfb += 4 * HH * WW * 4;    // +4 channels, bytes
    vob += 4 * HUP * WUP * 4;

    v2f acc0 = {0.f, 0.f}, acc1 = {0.f, 0.f};

    const v4f r0 = llvm_amdgcn_raw_buffer_load_v4f32(srdF, vfb + 0 * WW * 4, 0, 0);
    const float s0 = llvm_amdgcn_raw_buffer_load_fp32(srdF, vfb + 0 * WW * 4 + 16, 0, 0);
    const v4f r1 = llvm_amdgcn_raw_buffer_load_v4f32(srdF, vfb + 1 * WW * 4, 0, 0);
    const float s1 = llvm_amdgcn_raw_buffer_load_fp32(srdF, vfb + 1 * WW * 4 + 16, 0, 0);
    const v4f r2 = llvm_amdgcn_raw_buffer_load_v4f32(srdF, vfb + 2 * WW * 4, 0, 0);
    const float s2 = llvm_amdgcn_raw_buffer_load_fp32(srdF, vfb + 2 * WW * 4 + 16, 0, 0);
    FMA5(0,  r0.x, r0.y, r0.z, r0.w, s0);
    FMA5(5,  r1.x, r1.y, r1.z, r1.w, s1);
    FMA5(10, r2.x, r2.y, r2.z, r2.w, s2);

    const v4f r3 = llvm_amdgcn_raw_buffer_load_v4f32(srdF, vfb + 3 * WW * 4, 0, 0);
    const float s3 = llvm_amdgcn_raw_buffer_load_fp32(srdF, vfb + 3 * WW * 4 + 16, 0, 0);
    const v4f r4 = llvm_amdgcn_raw_buffer_load_v4f32(srdF, vfb + 4 * WW * 4, 0, 0);
    const float s4 = llvm_amdgcn_raw_buffer_load_fp32(srdF, vfb + 4 * WW * 4 + 16, 0, 0);
    FMA5(15, r3.x, r3.y, r3.z, r3.w, s3);
    FMA5(20, r4.x, r4.y, r4.z, r4.w, s4);

    llvm_amdgcn_raw_buffer_store_v2f32(acc0, srdO, vob, 0, 0);
    llvm_amdgcn_raw_buffer_store_v2f32(acc1, srdO, vob + WUP * 4, 0, 0);
  }
#undef FMA5
#undef FMA1
}

extern "C" void kernel_launch(void* const* d_in, const int* in_sizes, int n_in,
                              void* d_out, int out_size, void* d_ws, size_t ws_size,
                              hipStream_t stream) {
  const float* feat  = (const float*)d_in[0];
  const float* masks = (const float*)d_in[1];
  float* out = (float*)d_out;
  (void)in_sizes; (void)n_in; (void)out_size; (void)d_ws; (void)ws_size;
  carafe_kernel<<<NN * HH * 4, 256, 0, stream>>>(feat, masks, out);
}

// Round 8
// 26.312 us; speedup vs baseline: 1.4674x; 1.4674x over previous
//
#include <hip/hip_runtime.h>

#define NN 4
#define CC 128
#define HH 64
#define WW 64
#define KK 5
#define K2 25
#define HUP 128
#define WUP 128
#define OCH4 (4 * HUP * WUP * 4)    // output byte stride of 4 channels

typedef int   v4i __attribute__((ext_vector_type(4)));
typedef float v2f __attribute__((ext_vector_type(2)));

__device__ void llvm_amdgcn_raw_buffer_store_v2f32(v2f data, v4i srsrc,
                                                   int voffset, int soffset,
                                                   int aux)
    __asm("llvm.amdgcn.raw.buffer.store.v2f32");

__device__ inline v4i make_srd(const void* p, unsigned bytes) {
  union { const void* p; unsigned u[2]; } a;
  a.p = p;
  v4i r;
  r.x = (int)a.u[0];
  r.y = (int)(a.u[1] & 0xffffu);  // base[47:32], stride=0
  r.z = (int)bytes;               // num_records in bytes
  r.w = 0x00020000;               // raw dword access
  return r;
}

// grid: NN*HH*4 = 1024 blocks, 256 threads, 3 waves/SIMD (VGPR ~140, no spill).
// block: cq = bid&3, h = (bid>>2)&63, n = bid>>8
// thread: w = t&63 (output pair 2w,2w+1), cg = t>>6; c = cq*32 + ci*4 + cg
//
// Feature access: lane w loads exactly element w of each window row (perfectly
// coalesced, zero overlap); the 5 taps x=w-2..w+2 come from cross-lane
// shuffles. Taps with x outside [0,64) (incl. shfl mod-64 wrap) are
// annihilated by the vj-zeroed mask registers.
__global__ __launch_bounds__(256, 3) void carafe_kernel(
    const float* __restrict__ feat, const float* __restrict__ masks,
    float* __restrict__ out) {
  const int bid = blockIdx.x;
  const int cq = bid & 3;
  const int h  = (bid >> 2) & (HH - 1);
  const int n  = bid >> 8;
  const int t  = threadIdx.x;
  const int w  = t & (WW - 1);
  const int cg = t >> 6;

  // Validity of window taps (zero-padding folded into the mask registers).
  float vi[KK], vj[KK];
#pragma unroll
  for (int i = 0; i < KK; ++i) {
    const int r = h - 2 + i;
    vi[i] = (r >= 0 && r < HH) ? 1.f : 0.f;
    const int x = w - 2 + i;
    vj[i] = (x >= 0 && x < WW) ? 1.f : 0.f;
  }

  // mreg[k][a] = {masks[n,k,2h+a,2w], masks[n,k,2h+a,2w+1]} * valid(i,j)
  // (R4-proven pointer float2 path)
  v2f mreg[K2][2];
#pragma unroll
  for (int k = 0; k < K2; ++k) {
    const int i = k / KK, j = k % KK;
    const float vv = vi[i] * vj[j];
#pragma unroll
    for (int a = 0; a < 2; ++a) {
      const float2 mv = *reinterpret_cast<const float2*>(
          &masks[(((size_t)n * K2 + k) * HUP + (2 * h + a)) * WUP + 2 * w]);
      v2f m; m.x = mv.x * vv; m.y = mv.y * vv;
      mreg[k][a] = m;
    }
  }

  const v4i srdO = make_srd(out, (unsigned)(NN * CC * HUP * WUP) * 4u);

  // Clamped (always in-bounds) row offsets — invalid rows are vi-masked.
  int roff[KK];
#pragma unroll
  for (int i = 0; i < KK; ++i)
    roff[i] = min(max(h - 2 + i, 0), HH - 1) * WW;

  const int c = cq * 32 + cg;
  const float* fb = feat + (size_t)(n * CC + c) * (HH * WW) + w;
  int vob = (((n * CC + c) * HUP + 2 * h) * WUP + 2 * w) * 4;

  const int wm2 = w - 2, wm1 = w - 1, wp1 = w + 1, wp2 = w + 2;

#define FMA1(k, e)                                                       \
  do {                                                                   \
    v2f ff; ff.x = (e); ff.y = (e);                                      \
    acc0 += ff * mreg[k][0]; acc1 += ff * mreg[k][1];                    \
  } while (0)

#define FMAROW(kb, ROW)                                                  \
  do {                                                                   \
    const float t0 = __shfl((ROW), wm2);                                 \
    const float t1 = __shfl((ROW), wm1);                                 \
    const float t3 = __shfl((ROW), wp1);                                 \
    const float t4 = __shfl((ROW), wp2);                                 \
    FMA1((kb) + 0, t0); FMA1((kb) + 1, t1); FMA1((kb) + 2, (ROW));       \
    FMA1((kb) + 3, t3); FMA1((kb) + 4, t4);                              \
  } while (0)

#pragma unroll 1
  for (int ci = 0; ci < 8; ++ci) {
    // 5 clean coalesced row loads (lane w -> element w), issued together.
    const float r0 = fb[roff[0]];
    const float r1 = fb[roff[1]];
    const float r2 = fb[roff[2]];
    const float r3 = fb[roff[3]];
    const float r4 = fb[roff[4]];

    v2f acc0 = {0.f, 0.f}, acc1 = {0.f, 0.f};
    FMAROW(0,  r0);
    FMAROW(5,  r1);
    FMAROW(10, r2);
    FMAROW(15, r3);
    FMAROW(20, r4);

    llvm_amdgcn_raw_buffer_store_v2f32(acc0, srdO, vob, 0, 0);
    llvm_amdgcn_raw_buffer_store_v2f32(acc1, srdO, vob + WUP * 4, 0, 0);

    fb += 4 * HH * WW;   // +4 channels (cg-interleaved)
    vob += OCH4;
  }
#undef FMAROW
#undef FMA1
}

extern "C" void kernel_launch(void* const* d_in, const int* in_sizes, int n_in,
                              void* d_out, int out_size, void* d_ws, size_t ws_size,
                              hipStream_t stream) {
  const float* feat  = (const float*)d_in[0];
  const float* masks = (const float*)d_in[1];
  float* out = (float*)d_out;
  (void)in_sizes; (void)n_in; (void)out_size; (void)d_ws; (void)ws_size;
  carafe_kernel<<<NN * HH * 4, 256, 0, stream>>>(feat, masks, out);
}